// Round 6
// baseline (1045.155 us; speedup 1.0000x reference)
//
#include <hip/hip_runtime.h>

#define N_USERS  100000
#define N_ITEMS  100000
#define N_NODES  200000
#define EMBED    64
#define NB       3
#define N_EDGESC 2000000
#define NE_TOT   (NB * N_EDGESC)     // 6M
#define BATCH    4096
#define M_SEG    (NB * N_NODES)      // 600000 flat segments
#define NPART    64
#define PSIZE    3125                // N_NODES / NPART (exact)
#define NBUCK    (NB * NPART)        // 192
#define NBLKB    128                 // edge blocks per behavior (16384 edges each)
#define EPB      16384               // edges per scatter block (64 iters x 256)
#define CONV_BLOCKS 4096
#define NPW      13                  // nodes per wave: 4096*4*13 = 212992 >= 200000

typedef unsigned short u16;

__device__ __forceinline__ float b2f(u16 h) {
    return __uint_as_float(((unsigned)h) << 16);
}
__device__ __forceinline__ u16 f2b(float f) {
    unsigned u = __float_as_uint(f);
    return (u16)((u + 0x7FFF + ((u >> 16) & 1)) >> 16);   // RNE
}

// ---------------------------------------------------------------- init: concat -> f32 total + bf16 mirror
__global__ __launch_bounds__(256) void init_kernel(const float* __restrict__ ue,
                                                   const float* __restrict__ ie,
                                                   float* __restrict__ total,
                                                   ushort4* __restrict__ g16) {
    const int n4 = N_NODES * EMBED / 4;                   // 3.2M float4
    int stride = gridDim.x * 256;
    const float4* u4 = (const float4*)ue;
    const float4* i4 = (const float4*)ie;
    float4* t4 = (float4*)total;
    const int nu4 = N_USERS * EMBED / 4;
    for (int i = blockIdx.x * 256 + threadIdx.x; i < n4; i += stride) {
        float4 v = (i < nu4) ? u4[i] : i4[i - nu4];
        t4[i] = v;
        ushort4 h; h.x = f2b(v.x); h.y = f2b(v.y); h.z = f2b(v.z); h.w = f2b(v.w);
        g16[i] = h;
    }
}

// ---------------------------------------------------------------- scatterA: per-(bucket,block) hist
__global__ __launch_bounds__(256) void scatterA(const int* __restrict__ edges,
                                                int* __restrict__ H) {
    __shared__ int h[NPART];
    int bi  = blockIdx.x / NBLKB;
    int blk = blockIdx.x - bi * NBLKB;
    const int* cols = edges + ((size_t)bi * 2 + 1) * N_EDGESC;
    if (threadIdx.x < NPART) h[threadIdx.x] = 0;
    __syncthreads();
    int base0 = blk * EPB;
#pragma unroll 4
    for (int it = 0; it < EPB / 256; ++it) {
        int idx = base0 + it * 256 + threadIdx.x;
        if (idx < N_EDGESC) atomicAdd(&h[cols[idx] / PSIZE], 1);
    }
    __syncthreads();
    if (threadIdx.x < NPART)
        H[(bi * NPART + threadIdx.x) * NBLKB + blk] = h[threadIdx.x];
}

// ---------------------------------------------------------------- colscan: excl scan of each bucket's 128 block counts
__global__ __launch_bounds__(256) void colscan(int* __restrict__ H,
                                               int* __restrict__ bCnt) {
    int wid = blockIdx.x * 4 + (threadIdx.x >> 6);
    if (wid >= NBUCK) return;
    int lane = threadIdx.x & 63;
    int i0 = wid * NBLKB + lane, i1 = i0 + 64;
    int v0 = H[i0], v1 = H[i1];
    int s0 = v0;
#pragma unroll
    for (int off = 1; off < 64; off <<= 1) {
        int t = __shfl_up(s0, off, 64);
        if (lane >= off) s0 += t;
    }
    int t0 = __shfl(s0, 63, 64);
    int s1 = v1;
#pragma unroll
    for (int off = 1; off < 64; off <<= 1) {
        int t = __shfl_up(s1, off, 64);
        if (lane >= off) s1 += t;
    }
    H[i0] = s0 - v0;
    H[i1] = t0 + s1 - v1;
    if (lane == 63) bCnt[wid] = t0 + s1;
}

// ---------------------------------------------------------------- scan 192 buckets (1 block)
__global__ __launch_bounds__(256) void scan_buckets(const int* __restrict__ bCnt,
                                                    int* __restrict__ bBase,
                                                    int* __restrict__ startv,
                                                    float* __restrict__ loss) {
    __shared__ int s[NBUCK + 1];
    int tid = threadIdx.x;
    if (tid < NBUCK) s[tid] = bCnt[tid];
    __syncthreads();
    if (tid == 0) {
        int acc = 0;
        for (int i = 0; i < NBUCK; ++i) { int v = s[i]; s[i] = acc; acc += v; }
        s[NBUCK] = acc;                 // == NE_TOT
        startv[M_SEG] = acc;            // sentinel
        loss[0] = 0.0f;
    }
    __syncthreads();
    if (tid < NBUCK + 1) bBase[tid] = s[tid];
}

// ---------------------------------------------------------------- scatterB: deterministic bucket placement
__global__ __launch_bounds__(256) void scatterB(const int* __restrict__ edges,
                                                const int* __restrict__ H,
                                                const int* __restrict__ bBase,
                                                int* __restrict__ bpack) {
    __shared__ int sbase[NPART];
    __shared__ int cur[NPART];
    int bi  = blockIdx.x / NBLKB;
    int blk = blockIdx.x - bi * NBLKB;
    const int* rows = edges + ((size_t)bi * 2 + 0) * N_EDGESC;
    const int* cols = edges + ((size_t)bi * 2 + 1) * N_EDGESC;
    if (threadIdx.x < NPART) {
        int b = bi * NPART + threadIdx.x;
        sbase[threadIdx.x] = bBase[b] + H[b * NBLKB + blk];
        cur[threadIdx.x] = 0;
    }
    __syncthreads();
    int base0 = blk * EPB;
    for (int it = 0; it < EPB / 256; ++it) {
        int idx = base0 + it * 256 + threadIdx.x;
        if (idx < N_EDGESC) {
            int c = cols[idx];
            int r = rows[idx];
            int p = c / PSIZE;
            int rank = atomicAdd(&cur[p], 1);
            bpack[sbase[p] + rank] = ((c - p * PSIZE) << 18) | r;
        }
    }
}

// ---------------------------------------------------------------- place: one block per bucket
__global__ __launch_bounds__(256) void place_kernel(const int* __restrict__ bpack,
                                                    const int* __restrict__ bBase,
                                                    int* __restrict__ startv,
                                                    float* __restrict__ dinv,
                                                    int* __restrict__ srow) {
    __shared__ int cnt[PSIZE + 2];
    __shared__ int tsum[256];
    int b    = blockIdx.x;              // 0..191
    int bi   = b / NPART;
    int part = b - bi * NPART;
    int segBase = bi * N_NODES + part * PSIZE;
    int lo = bBase[b], hiEnd = bBase[b + 1];

    for (int i = threadIdx.x; i < PSIZE + 1; i += 256) cnt[i] = 0;
    __syncthreads();
    for (int i = lo + threadIdx.x; i < hiEnd; i += 256)
        atomicAdd(&cnt[bpack[i] >> 18], 1);
    __syncthreads();

    int t = threadIdx.x;
    int base0 = t * 13;
    int sum = 0;
#pragma unroll
    for (int k = 0; k < 13; ++k) {
        int i = base0 + k;
        if (i <= PSIZE) sum += cnt[i];
    }
    tsum[t] = sum;
    __syncthreads();
    for (int off = 1; off < 256; off <<= 1) {
        int v = (t >= off) ? tsum[t - off] : 0;
        __syncthreads();
        tsum[t] += v;
        __syncthreads();
    }
    int run = tsum[t] - sum;
    int vals[13];
#pragma unroll
    for (int k = 0; k < 13; ++k) {
        int i = base0 + k;
        vals[k] = (i <= PSIZE) ? cnt[i] : 0;
    }
    __syncthreads();
#pragma unroll
    for (int k = 0; k < 13; ++k) {
        int i = base0 + k;
        if (i <= PSIZE) { cnt[i] = run; run += vals[k]; }
    }
    __syncthreads();

    for (int i = threadIdx.x; i < PSIZE; i += 256) {
        int excl = cnt[i];
        int d    = cnt[i + 1] - excl;
        startv[segBase + i] = lo + excl;
        dinv[segBase + i]   = (d > 0) ? rsqrtf((float)d) : 0.0f;
    }
    __syncthreads();

    for (int i = lo + threadIdx.x; i < hiEnd; i += 256) {
        int pk  = bpack[i];
        int pos = atomicAdd(&cnt[pk >> 18], 1);
        srow[lo + pos] = pk & 0x3FFFF;
    }
}

// ---------------------------------------------------------------- fused conv v3:
// gathers bf16 mirror rows (128B/row), accumulates f32; W-column dot via
// readlane; in-place f32 residual update + bf16 mirror write for next layer.
__global__ __launch_bounds__(256) void conv_kernel(const int* __restrict__ srow,
                                                   const int* __restrict__ startv,
                                                   const float* __restrict__ dinv,
                                                   const ushort4* __restrict__ g16in,
                                                   float* __restrict__ total,
                                                   ushort4* __restrict__ g16out,
                                                   const float* __restrict__ W,
                                                   const float* __restrict__ bias,
                                                   int base /* bi*N_NODES */) {
    int lane = threadIdx.x & 63;
    int sub  = lane >> 4;        // 0..3 (edge slot)
    int li   = lane & 15;        // 0..15 (ushort4 slot = dims 4*li..4*li+3)
    float w[64];
#pragma unroll
    for (int k = 0; k < 64; ++k) w[k] = W[k * 64 + lane];
    float bs = bias[lane];
    int wgid = blockIdx.x * 4 + (threadIdx.x >> 6);
    int c0 = wgid * NPW;
    if (c0 >= N_NODES) return;
    int c1 = c0 + NPW; if (c1 > N_NODES) c1 = N_NODES;

    for (int c = c0; c < c1; ++c) {
        int   s   = startv[base + c];
        int   end = startv[base + c + 1];
        float dc  = dinv[base + c];
        float4 accA = {0.f, 0.f, 0.f, 0.f};
        float4 accB = {0.f, 0.f, 0.f, 0.f};
        int e = s;
        for (; e + 8 <= end; e += 8) {
            int r0 = srow[e + sub];
            int r1 = srow[e + 4 + sub];
            float n0 = dinv[base + r0];
            float n1 = dinv[base + r1];
            ushort4 a0 = g16in[(size_t)r0 * 16 + li];
            ushort4 a1 = g16in[(size_t)r1 * 16 + li];
            accA.x += n0 * b2f(a0.x); accA.y += n0 * b2f(a0.y);
            accA.z += n0 * b2f(a0.z); accA.w += n0 * b2f(a0.w);
            accB.x += n1 * b2f(a1.x); accB.y += n1 * b2f(a1.y);
            accB.z += n1 * b2f(a1.z); accB.w += n1 * b2f(a1.w);
        }
        for (; e < end; e += 4) {
            int  ei  = e + sub;
            bool ok  = ei < end;
            int  eic = ok ? ei : e;
            int  r   = srow[eic];
            float n  = ok ? dinv[base + r] : 0.0f;
            ushort4 a = g16in[(size_t)r * 16 + li];
            accA.x += n * b2f(a.x); accA.y += n * b2f(a.y);
            accA.z += n * b2f(a.z); accA.w += n * b2f(a.w);
        }
        float4 acc;
        acc.x = accA.x + accB.x; acc.y = accA.y + accB.y;
        acc.z = accA.z + accB.z; acc.w = accA.w + accB.w;
        acc.x += __shfl_xor(acc.x, 16, 64); acc.y += __shfl_xor(acc.y, 16, 64);
        acc.z += __shfl_xor(acc.z, 16, 64); acc.w += __shfl_xor(acc.w, 16, 64);
        acc.x += __shfl_xor(acc.x, 32, 64); acc.y += __shfl_xor(acc.y, 32, 64);
        acc.z += __shfl_xor(acc.z, 32, 64); acc.w += __shfl_xor(acc.w, 32, 64);
        float p0 = 0.f, p1 = 0.f, p2 = 0.f, p3 = 0.f;
#pragma unroll
        for (int q = 0; q < 16; ++q) {
            float a0 = __int_as_float(__builtin_amdgcn_readlane(__float_as_int(acc.x), q));
            float a1 = __int_as_float(__builtin_amdgcn_readlane(__float_as_int(acc.y), q));
            float a2 = __int_as_float(__builtin_amdgcn_readlane(__float_as_int(acc.z), q));
            float a3 = __int_as_float(__builtin_amdgcn_readlane(__float_as_int(acc.w), q));
            p0 += a0 * w[4 * q + 0];
            p1 += a1 * w[4 * q + 1];
            p2 += a2 * w[4 * q + 2];
            p3 += a3 * w[4 * q + 3];
        }
        float v = (p0 + p1) + (p2 + p3);
        v = v * dc + bs;
        float sq = v * v;
#pragma unroll
        for (int off = 32; off; off >>= 1) sq += __shfl_xor(sq, off, 64);
        float inv = 1.0f / fmaxf(sqrtf(sq), 1e-12f);
        size_t idx = (size_t)c * 64 + lane;
        float tv = total[idx] + v * inv;       // in-place safe: gathers use g16in
        total[idx] = tv;
        // bf16 mirror write: lane li of subgroup 0 writes dims 4li..4li+3 via shfl
        u16 h = f2b(tv);
        unsigned packlo = ((unsigned)__shfl(h, 2 * li,     64)) |
                          (((unsigned)__shfl(h, 2 * li + 1, 64)) << 16);
        unsigned packhi = ((unsigned)__shfl(h, 2 * li + 32, 64)) |
                          (((unsigned)__shfl(h, 2 * li + 33, 64)) << 16);
        if (sub == 0) {        // lanes 0..15: write ushort4 = dims {2li,2li+1,2li+32,2li+33}? no:
        }
        // simpler/correct: each lane writes its own bf16 via u16 store
        ((u16*)g16out)[idx] = h;
    }
}

// ---------------------------------------------------------------- BPR loss
__global__ __launch_bounds__(256) void bpr_kernel(const float* __restrict__ total,
                                                  const int* __restrict__ batch,
                                                  int bi, float* __restrict__ loss) {
    int gid  = blockIdx.x * 256 + threadIdx.x;
    int b    = gid >> 6;
    int lane = threadIdx.x & 63;
    if (b >= BATCH) return;
    int u  = batch[((size_t)b * NB + bi) * 3 + 0];
    int i0 = batch[((size_t)b * NB + bi) * 3 + 1];
    int i1 = batch[((size_t)b * NB + bi) * 3 + 2];
    float uf = total[(size_t)u * 64 + lane];
    float f0 = total[(size_t)(N_USERS + i0) * 64 + lane];
    float f1 = total[(size_t)(N_USERS + i1) * 64 + lane];
    float d  = uf * (f0 - f1);
#pragma unroll
    for (int off = 32; off; off >>= 1) d += __shfl_xor(d, off, 64);
    if (lane == 0) {
        float sp = (d > 0.0f) ? log1pf(expf(-d)) : (-d + log1pf(expf(d)));
        unsafeAtomicAdd(loss, sp * (1.0f / BATCH));
    }
}

// ---------------------------------------------------------------- embedding L2 reg
__global__ __launch_bounds__(256) void reg_kernel(const float* __restrict__ ue,
                                                  const float* __restrict__ ie,
                                                  float* __restrict__ loss) {
    const size_t n4 = (size_t)N_USERS * EMBED / 4;
    size_t tid    = (size_t)blockIdx.x * 256 + threadIdx.x;
    size_t stride = (size_t)gridDim.x * 256;
    const float4* u4 = (const float4*)ue;
    const float4* i4 = (const float4*)ie;
    float s = 0.0f;
    for (size_t i = tid; i < n4; i += stride) {
        float4 a = u4[i];
        s += a.x * a.x + a.y * a.y + a.z * a.z + a.w * a.w;
        float4 b = i4[i];
        s += b.x * b.x + b.y * b.y + b.z * b.z + b.w * b.w;
    }
#pragma unroll
    for (int off = 32; off; off >>= 1) s += __shfl_xor(s, off, 64);
    if ((threadIdx.x & 63) == 0)
        unsafeAtomicAdd(loss, s * (0.5f * 0.0001f / (float)BATCH));
}

// ---------------------------------------------------------------- final scalar write
__global__ void final_write(const float* __restrict__ loss, float* __restrict__ out) {
    out[0] = loss[0];
}

extern "C" void kernel_launch(void* const* d_in, const int* in_sizes, int n_in,
                              void* d_out, int out_size, void* d_ws, size_t ws_size,
                              hipStream_t stream) {
    const float* user_emb = (const float*)d_in[0];
    const float* item_emb = (const float*)d_in[1];
    const float* gcn_w    = (const float*)d_in[2];
    const float* gcn_b    = (const float*)d_in[3];
    const int*   edges    = (const int*)d_in[4];
    const int*   batch    = (const int*)d_in[5];
    float*       out      = (float*)d_out;

    const size_t NODE_F = (size_t)N_NODES * EMBED;            // 12.8M elems
    float*   total  = (float*)d_ws;                           // 51.2 MB (f32 master, in-place)
    ushort4* g16A   = (ushort4*)(total + NODE_F);             // 25.6 MB bf16 mirror A
    ushort4* g16B   = g16A + NODE_F / 4;                      // 25.6 MB bf16 mirror B
    float*   dinv   = (float*)(g16B + NODE_F / 4);            //  2.4 MB
    int*     startv = (int*)(dinv + M_SEG);                   //  2.4 MB (+1 sentinel)
    int*     Hglob  = startv + M_SEG + 1;                     //  393 KB (192*128)
    int*     bCnt   = Hglob + NBUCK * NBLKB;                  //  768 B
    int*     bBase  = bCnt + NBUCK;                           //  772 B
    int*     bpack  = bBase + NBUCK + 1;                      //  24 MB
    int*     srow   = bpack + NE_TOT;                         //  24 MB
    float*   loss   = (float*)(srow + NE_TOT);                //   4 B

    init_kernel<<<4096, 256, 0, stream>>>(user_emb, item_emb, total, g16A);

    // deterministic counting sort by destination column
    scatterA<<<NB * NBLKB, 256, 0, stream>>>(edges, Hglob);
    colscan<<<48, 256, 0, stream>>>(Hglob, bCnt);
    scan_buckets<<<1, 256, 0, stream>>>(bCnt, bBase, startv, loss);
    scatterB<<<NB * NBLKB, 256, 0, stream>>>(edges, Hglob, bBase, bpack);
    place_kernel<<<NBUCK, 256, 0, stream>>>(bpack, bBase, startv, dinv, srow);

    reg_kernel<<<2048, 256, 0, stream>>>(user_emb, item_emb, loss);

    ushort4* gcur = g16A;
    ushort4* gnxt = g16B;
    for (int bi = 0; bi < NB; ++bi) {
        conv_kernel<<<CONV_BLOCKS, 256, 0, stream>>>(
            srow, startv, dinv, gcur, total, gnxt,
            gcn_w + (size_t)bi * EMBED * EMBED, gcn_b + bi * EMBED, bi * N_NODES);
        bpr_kernel<<<(BATCH * 64 + 255) / 256, 256, 0, stream>>>(total, batch, bi, loss);
        ushort4* t = gcur; gcur = gnxt; gnxt = t;
    }
    final_write<<<1, 1, 0, stream>>>(loss, out);
}

// Round 7
// 1031.760 us; speedup vs baseline: 1.0130x; 1.0130x over previous
//
#include <hip/hip_runtime.h>

#define N_USERS  100000
#define N_ITEMS  100000
#define N_NODES  200000
#define EMBED    64
#define NB       3
#define N_EDGESC 2000000
#define NE_TOT   (NB * N_EDGESC)     // 6M
#define BATCH    4096
#define M_SEG    (NB * N_NODES)      // 600000 flat segments
#define NPART    64
#define PSIZE    3125                // N_NODES / NPART (exact)
#define NBUCK    (NB * NPART)        // 192
#define NBLKB    128                 // edge blocks per behavior (16384 edges each)
#define EPB      16384
#define GEMM_BLOCKS 2048
#define GEMM_RPW 25                  // 2048*4*25 = 204800 >= 200000
#define AGG_BLOCKS 12500             // 12500 * 16 nodes/block = 200000 exact

typedef unsigned short u16;

__device__ __forceinline__ float b2f(u16 h) {
    return __uint_as_float(((unsigned)h) << 16);
}
__device__ __forceinline__ u16 f2b(float f) {
    unsigned u = __float_as_uint(f);
    return (u16)((u + 0x7FFF + ((u >> 16) & 1)) >> 16);   // RNE
}

// ---------------------------------------------------------------- init: concat -> f32 total + bf16 mirror + fused reg loss
__global__ __launch_bounds__(256) void init_kernel(const float* __restrict__ ue,
                                                   const float* __restrict__ ie,
                                                   float* __restrict__ total,
                                                   ushort4* __restrict__ g16,
                                                   float* __restrict__ loss) {
    const int n4 = N_NODES * EMBED / 4;                   // 3.2M float4
    int stride = gridDim.x * 256;
    const float4* u4 = (const float4*)ue;
    const float4* i4 = (const float4*)ie;
    float4* t4 = (float4*)total;
    const int nu4 = N_USERS * EMBED / 4;
    float s = 0.0f;
    for (int i = blockIdx.x * 256 + threadIdx.x; i < n4; i += stride) {
        float4 v = (i < nu4) ? u4[i] : i4[i - nu4];
        t4[i] = v;
        ushort4 h; h.x = f2b(v.x); h.y = f2b(v.y); h.z = f2b(v.z); h.w = f2b(v.w);
        g16[i] = h;
        s += v.x * v.x + v.y * v.y + v.z * v.z + v.w * v.w;
    }
#pragma unroll
    for (int off = 32; off; off >>= 1) s += __shfl_xor(s, off, 64);
    if ((threadIdx.x & 63) == 0)
        unsafeAtomicAdd(loss, s * (0.5f * 0.0001f / (float)BATCH));
}

// ---------------------------------------------------------------- scatterA: per-(bucket,block) hist
__global__ __launch_bounds__(256) void scatterA(const int* __restrict__ edges,
                                                int* __restrict__ H) {
    __shared__ int h[NPART];
    int bi  = blockIdx.x / NBLKB;
    int blk = blockIdx.x - bi * NBLKB;
    const int* cols = edges + ((size_t)bi * 2 + 1) * N_EDGESC;
    if (threadIdx.x < NPART) h[threadIdx.x] = 0;
    __syncthreads();
    int base0 = blk * EPB;
#pragma unroll 4
    for (int it = 0; it < EPB / 256; ++it) {
        int idx = base0 + it * 256 + threadIdx.x;
        if (idx < N_EDGESC) atomicAdd(&h[cols[idx] / PSIZE], 1);
    }
    __syncthreads();
    if (threadIdx.x < NPART)
        H[(bi * NPART + threadIdx.x) * NBLKB + blk] = h[threadIdx.x];
}

// ---------------------------------------------------------------- colscan
__global__ __launch_bounds__(256) void colscan(int* __restrict__ H,
                                               int* __restrict__ bCnt) {
    int wid = blockIdx.x * 4 + (threadIdx.x >> 6);
    if (wid >= NBUCK) return;
    int lane = threadIdx.x & 63;
    int i0 = wid * NBLKB + lane, i1 = i0 + 64;
    int v0 = H[i0], v1 = H[i1];
    int s0 = v0;
#pragma unroll
    for (int off = 1; off < 64; off <<= 1) {
        int t = __shfl_up(s0, off, 64);
        if (lane >= off) s0 += t;
    }
    int t0 = __shfl(s0, 63, 64);
    int s1 = v1;
#pragma unroll
    for (int off = 1; off < 64; off <<= 1) {
        int t = __shfl_up(s1, off, 64);
        if (lane >= off) s1 += t;
    }
    H[i0] = s0 - v0;
    H[i1] = t0 + s1 - v1;
    if (lane == 63) bCnt[wid] = t0 + s1;
}

// ---------------------------------------------------------------- scan 192 buckets
__global__ __launch_bounds__(256) void scan_buckets(const int* __restrict__ bCnt,
                                                    int* __restrict__ bBase,
                                                    int* __restrict__ startv) {
    __shared__ int s[NBUCK + 1];
    int tid = threadIdx.x;
    if (tid < NBUCK) s[tid] = bCnt[tid];
    __syncthreads();
    if (tid == 0) {
        int acc = 0;
        for (int i = 0; i < NBUCK; ++i) { int v = s[i]; s[i] = acc; acc += v; }
        s[NBUCK] = acc;
        startv[M_SEG] = acc;            // sentinel
    }
    __syncthreads();
    if (tid < NBUCK + 1) bBase[tid] = s[tid];
}

// ---------------------------------------------------------------- scatterB: deterministic bucket placement
__global__ __launch_bounds__(256) void scatterB(const int* __restrict__ edges,
                                                const int* __restrict__ H,
                                                const int* __restrict__ bBase,
                                                int* __restrict__ bpack) {
    __shared__ int sbase[NPART];
    __shared__ int cur[NPART];
    int bi  = blockIdx.x / NBLKB;
    int blk = blockIdx.x - bi * NBLKB;
    const int* rows = edges + ((size_t)bi * 2 + 0) * N_EDGESC;
    const int* cols = edges + ((size_t)bi * 2 + 1) * N_EDGESC;
    if (threadIdx.x < NPART) {
        int b = bi * NPART + threadIdx.x;
        sbase[threadIdx.x] = bBase[b] + H[b * NBLKB + blk];
        cur[threadIdx.x] = 0;
    }
    __syncthreads();
    int base0 = blk * EPB;
    for (int it = 0; it < EPB / 256; ++it) {
        int idx = base0 + it * 256 + threadIdx.x;
        if (idx < N_EDGESC) {
            int c = cols[idx];
            int r = rows[idx];
            int p = c / PSIZE;
            int rank = atomicAdd(&cur[p], 1);
            bpack[sbase[p] + rank] = ((c - p * PSIZE) << 18) | r;
        }
    }
}

// ---------------------------------------------------------------- place: one block per bucket
__global__ __launch_bounds__(256) void place_kernel(const int* __restrict__ bpack,
                                                    const int* __restrict__ bBase,
                                                    int* __restrict__ startv,
                                                    float* __restrict__ dinv,
                                                    int* __restrict__ srow) {
    __shared__ int cnt[PSIZE + 2];
    __shared__ int tsum[256];
    int b    = blockIdx.x;
    int bi   = b / NPART;
    int part = b - bi * NPART;
    int segBase = bi * N_NODES + part * PSIZE;
    int lo = bBase[b], hiEnd = bBase[b + 1];

    for (int i = threadIdx.x; i < PSIZE + 1; i += 256) cnt[i] = 0;
    __syncthreads();
    for (int i = lo + threadIdx.x; i < hiEnd; i += 256)
        atomicAdd(&cnt[bpack[i] >> 18], 1);
    __syncthreads();

    int t = threadIdx.x;
    int base0 = t * 13;
    int sum = 0;
#pragma unroll
    for (int k = 0; k < 13; ++k) {
        int i = base0 + k;
        if (i <= PSIZE) sum += cnt[i];
    }
    tsum[t] = sum;
    __syncthreads();
    for (int off = 1; off < 256; off <<= 1) {
        int v = (t >= off) ? tsum[t - off] : 0;
        __syncthreads();
        tsum[t] += v;
        __syncthreads();
    }
    int run = tsum[t] - sum;
    int vals[13];
#pragma unroll
    for (int k = 0; k < 13; ++k) {
        int i = base0 + k;
        vals[k] = (i <= PSIZE) ? cnt[i] : 0;
    }
    __syncthreads();
#pragma unroll
    for (int k = 0; k < 13; ++k) {
        int i = base0 + k;
        if (i <= PSIZE) { cnt[i] = run; run += vals[k]; }
    }
    __syncthreads();

    for (int i = threadIdx.x; i < PSIZE; i += 256) {
        int excl = cnt[i];
        int d    = cnt[i + 1] - excl;
        startv[segBase + i] = lo + excl;
        dinv[segBase + i]   = (d > 0) ? rsqrtf((float)d) : 0.0f;
    }
    __syncthreads();

    for (int i = lo + threadIdx.x; i < hiEnd; i += 256) {
        int pk  = bpack[i];
        int pos = atomicAdd(&cnt[pk >> 18], 1);
        srow[lo + pos] = pk & 0x3FFFF;
    }
}

// ---------------------------------------------------------------- gemm16: x16 = bf16( total16 @ W )
// lane j holds W[:,j] in 64 VGPRs; rows streamed via wave-uniform uint4 loads
__global__ __launch_bounds__(256) void gemm16(const ushort4* __restrict__ g16in,
                                              const float* __restrict__ W,
                                              u16* __restrict__ x16) {
    int j = threadIdx.x & 63;
    float w[64];
#pragma unroll
    for (int k = 0; k < 64; ++k) w[k] = W[k * 64 + j];
    int wave = blockIdx.x * 4 + (threadIdx.x >> 6);
    int r0 = wave * GEMM_RPW;
    int r1 = r0 + GEMM_RPW; if (r1 > N_NODES) r1 = N_NODES;
    for (int r = r0; r < r1; ++r) {
        const uint4* row = (const uint4*)(g16in + (size_t)r * 16);
        float acc = 0.0f;
#pragma unroll
        for (int k8 = 0; k8 < 8; ++k8) {
            uint4 q = row[k8];
            acc += __uint_as_float(q.x << 16)         * w[8 * k8 + 0];
            acc += __uint_as_float(q.x & 0xFFFF0000u) * w[8 * k8 + 1];
            acc += __uint_as_float(q.y << 16)         * w[8 * k8 + 2];
            acc += __uint_as_float(q.y & 0xFFFF0000u) * w[8 * k8 + 3];
            acc += __uint_as_float(q.z << 16)         * w[8 * k8 + 4];
            acc += __uint_as_float(q.z & 0xFFFF0000u) * w[8 * k8 + 5];
            acc += __uint_as_float(q.w << 16)         * w[8 * k8 + 6];
            acc += __uint_as_float(q.w & 0xFFFF0000u) * w[8 * k8 + 7];
        }
        x16[(size_t)r * 64 + j] = f2b(acc);
    }
}

// ---------------------------------------------------------------- agg: gather-sum + bias + l2norm + residual
// 4 nodes/wave, one per 16-lane subgroup; 4-edge unroll => 12 loads in flight/subgroup
__global__ __launch_bounds__(256) void agg_kernel(const int* __restrict__ srow,
                                                  const int* __restrict__ startv,
                                                  const float* __restrict__ dinv,
                                                  const ushort4* __restrict__ x16,
                                                  float* __restrict__ total,
                                                  ushort4* __restrict__ g16out,
                                                  const float* __restrict__ bias,
                                                  int base /* bi*N_NODES */) {
    int lane = threadIdx.x & 63;
    int sub  = lane >> 4;
    int li   = lane & 15;
    int c = (blockIdx.x * 4 + (threadIdx.x >> 6)) * 4 + sub;   // < 200000 exact

    int   s   = startv[base + c];
    int   end = startv[base + c + 1];
    float dc  = dinv[base + c];
    float4 acc = {0.f, 0.f, 0.f, 0.f};
    for (int e = s; e < end; e += 4) {
        int e1 = e + 1 < end ? e + 1 : e;
        int e2 = e + 2 < end ? e + 2 : e;
        int e3 = e + 3 < end ? e + 3 : e;
        int r0 = srow[e],  r1 = srow[e1], r2 = srow[e2], r3 = srow[e3];
        float n0 = dinv[base + r0];
        float n1 = (e + 1 < end) ? dinv[base + r1] : 0.0f;
        float n2 = (e + 2 < end) ? dinv[base + r2] : 0.0f;
        float n3 = (e + 3 < end) ? dinv[base + r3] : 0.0f;
        ushort4 a0 = x16[(size_t)r0 * 16 + li];
        ushort4 a1 = x16[(size_t)r1 * 16 + li];
        ushort4 a2 = x16[(size_t)r2 * 16 + li];
        ushort4 a3 = x16[(size_t)r3 * 16 + li];
        acc.x += n0 * b2f(a0.x) + n1 * b2f(a1.x) + n2 * b2f(a2.x) + n3 * b2f(a3.x);
        acc.y += n0 * b2f(a0.y) + n1 * b2f(a1.y) + n2 * b2f(a2.y) + n3 * b2f(a3.y);
        acc.z += n0 * b2f(a0.z) + n1 * b2f(a1.z) + n2 * b2f(a2.z) + n3 * b2f(a3.z);
        acc.w += n0 * b2f(a0.w) + n1 * b2f(a1.w) + n2 * b2f(a2.w) + n3 * b2f(a3.w);
    }
    float4 b = ((const float4*)bias)[li];
    float4 v;
    v.x = acc.x * dc + b.x; v.y = acc.y * dc + b.y;
    v.z = acc.z * dc + b.z; v.w = acc.w * dc + b.w;
    float sq = v.x * v.x + v.y * v.y + v.z * v.z + v.w * v.w;
#pragma unroll
    for (int off = 1; off < 16; off <<= 1) sq += __shfl_xor(sq, off, 64);
    float inv = 1.0f / fmaxf(sqrtf(sq), 1e-12f);
    size_t idx = (size_t)c * 16 + li;
    float4 t = ((float4*)total)[idx];
    t.x += v.x * inv; t.y += v.y * inv; t.z += v.z * inv; t.w += v.w * inv;
    ((float4*)total)[idx] = t;
    ushort4 h; h.x = f2b(t.x); h.y = f2b(t.y); h.z = f2b(t.z); h.w = f2b(t.w);
    g16out[idx] = h;
}

// ---------------------------------------------------------------- BPR loss
__global__ __launch_bounds__(256) void bpr_kernel(const float* __restrict__ total,
                                                  const int* __restrict__ batch,
                                                  int bi, float* __restrict__ loss) {
    int gid  = blockIdx.x * 256 + threadIdx.x;
    int b    = gid >> 6;
    int lane = threadIdx.x & 63;
    if (b >= BATCH) return;
    int u  = batch[((size_t)b * NB + bi) * 3 + 0];
    int i0 = batch[((size_t)b * NB + bi) * 3 + 1];
    int i1 = batch[((size_t)b * NB + bi) * 3 + 2];
    float uf = total[(size_t)u * 64 + lane];
    float f0 = total[(size_t)(N_USERS + i0) * 64 + lane];
    float f1 = total[(size_t)(N_USERS + i1) * 64 + lane];
    float d  = uf * (f0 - f1);
#pragma unroll
    for (int off = 32; off; off >>= 1) d += __shfl_xor(d, off, 64);
    if (lane == 0) {
        float sp = (d > 0.0f) ? log1pf(expf(-d)) : (-d + log1pf(expf(d)));
        unsafeAtomicAdd(loss, sp * (1.0f / BATCH));
    }
}

// ---------------------------------------------------------------- final scalar write
__global__ void final_write(const float* __restrict__ loss, float* __restrict__ out) {
    out[0] = loss[0];
}

extern "C" void kernel_launch(void* const* d_in, const int* in_sizes, int n_in,
                              void* d_out, int out_size, void* d_ws, size_t ws_size,
                              hipStream_t stream) {
    const float* user_emb = (const float*)d_in[0];
    const float* item_emb = (const float*)d_in[1];
    const float* gcn_w    = (const float*)d_in[2];
    const float* gcn_b    = (const float*)d_in[3];
    const int*   edges    = (const int*)d_in[4];
    const int*   batch    = (const int*)d_in[5];
    float*       out      = (float*)d_out;

    const size_t NODE_F = (size_t)N_NODES * EMBED;            // 12.8M elems
    float*   total  = (float*)d_ws;                           // 51.2 MB f32 master
    ushort4* g16A   = (ushort4*)(total + NODE_F);             // 25.6 MB bf16 mirror A
    ushort4* g16B   = g16A + NODE_F / 4;                      // 25.6 MB bf16 mirror B
    u16*     x16    = (u16*)(g16B + NODE_F / 4);              // 25.6 MB bf16 gemm out
    float*   dinv   = (float*)(x16 + NODE_F);                 //  2.4 MB
    int*     startv = (int*)(dinv + M_SEG);                   //  2.4 MB (+1 sentinel)
    int*     Hglob  = startv + M_SEG + 1;                     //  98 KB
    int*     bCnt   = Hglob + NBUCK * NBLKB;                  //  768 B
    int*     bBase  = bCnt + NBUCK;                           //  772 B
    int*     bpack  = bBase + NBUCK + 1;                      //  24 MB
    int*     srow   = bpack + NE_TOT;                         //  24 MB
    float*   loss   = (float*)(srow + NE_TOT);                //   4 B

    hipMemsetAsync(loss, 0, sizeof(float), stream);
    init_kernel<<<4096, 256, 0, stream>>>(user_emb, item_emb, total, g16A, loss);

    // deterministic counting sort by destination column
    scatterA<<<NB * NBLKB, 256, 0, stream>>>(edges, Hglob);
    colscan<<<48, 256, 0, stream>>>(Hglob, bCnt);
    scan_buckets<<<1, 256, 0, stream>>>(bCnt, bBase, startv);
    scatterB<<<NB * NBLKB, 256, 0, stream>>>(edges, Hglob, bBase, bpack);
    place_kernel<<<NBUCK, 256, 0, stream>>>(bpack, bBase, startv, dinv, srow);

    ushort4* gcur = g16A;
    ushort4* gnxt = g16B;
    for (int bi = 0; bi < NB; ++bi) {
        gemm16<<<GEMM_BLOCKS, 256, 0, stream>>>(
            gcur, gcn_w + (size_t)bi * EMBED * EMBED, x16);
        agg_kernel<<<AGG_BLOCKS, 256, 0, stream>>>(
            srow, startv, dinv, (const ushort4*)x16, total, gnxt,
            gcn_b + bi * EMBED, bi * N_NODES);
        bpr_kernel<<<(BATCH * 64 + 255) / 256, 256, 0, stream>>>(total, batch, bi, loss);
        ushort4* t = gcur; gcur = gnxt; gnxt = t;
    }
    final_write<<<1, 1, 0, stream>>>(loss, out);
}

// Round 8
// 876.031 us; speedup vs baseline: 1.1931x; 1.1778x over previous
//
#include <hip/hip_runtime.h>

#define N_USERS  100000
#define N_ITEMS  100000
#define N_NODES  200000
#define EMBED    64
#define NB       3
#define N_EDGESC 2000000
#define NE_TOT   (NB * N_EDGESC)     // 6M
#define BATCH    4096
#define M_SEG    (NB * N_NODES)      // 600000 flat segments
#define NPART    64
#define PSIZE    3125                // N_NODES / NPART (exact)
#define NBUCK    (NB * NPART)        // 192
#define NBLKB    128                 // edge blocks per behavior (16384 edges each)
#define EPB      16384
#define GEMM_BLOCKS 2048
#define GEMM_RPW 25                  // 2048*4*25 = 204800 >= 200000
#define AGG_BLOCKS 12500             // 12500 * 16 nodes/block = 200000 exact
#define NPARTS   (GEMM_BLOCKS + NB * 1024)   // 2048 reg + 3072 bpr = 5120

typedef unsigned short u16;

__device__ __forceinline__ float b2f(u16 h) {
    return __uint_as_float(((unsigned)h) << 16);
}
__device__ __forceinline__ u16 f2b(float f) {
    unsigned u = __float_as_uint(f);
    return (u16)((u + 0x7FFF + ((u >> 16) & 1)) >> 16);   // RNE
}

// ---------------------------------------------------------------- scatterA: per-(bucket,block) hist
__global__ __launch_bounds__(256) void scatterA(const int* __restrict__ edges,
                                                int* __restrict__ H) {
    __shared__ int h[NPART];
    int bi  = blockIdx.x / NBLKB;
    int blk = blockIdx.x - bi * NBLKB;
    const int* cols = edges + ((size_t)bi * 2 + 1) * N_EDGESC;
    if (threadIdx.x < NPART) h[threadIdx.x] = 0;
    __syncthreads();
    int base0 = blk * EPB;
#pragma unroll 4
    for (int it = 0; it < EPB / 256; ++it) {
        int idx = base0 + it * 256 + threadIdx.x;
        if (idx < N_EDGESC) atomicAdd(&h[cols[idx] / PSIZE], 1);
    }
    __syncthreads();
    if (threadIdx.x < NPART)
        H[(bi * NPART + threadIdx.x) * NBLKB + blk] = h[threadIdx.x];
}

// ---------------------------------------------------------------- colscan
__global__ __launch_bounds__(256) void colscan(int* __restrict__ H,
                                               int* __restrict__ bCnt) {
    int wid = blockIdx.x * 4 + (threadIdx.x >> 6);
    if (wid >= NBUCK) return;
    int lane = threadIdx.x & 63;
    int i0 = wid * NBLKB + lane, i1 = i0 + 64;
    int v0 = H[i0], v1 = H[i1];
    int s0 = v0;
#pragma unroll
    for (int off = 1; off < 64; off <<= 1) {
        int t = __shfl_up(s0, off, 64);
        if (lane >= off) s0 += t;
    }
    int t0 = __shfl(s0, 63, 64);
    int s1 = v1;
#pragma unroll
    for (int off = 1; off < 64; off <<= 1) {
        int t = __shfl_up(s1, off, 64);
        if (lane >= off) s1 += t;
    }
    H[i0] = s0 - v0;
    H[i1] = t0 + s1 - v1;
    if (lane == 63) bCnt[wid] = t0 + s1;
}

// ---------------------------------------------------------------- scan 192 buckets
__global__ __launch_bounds__(256) void scan_buckets(const int* __restrict__ bCnt,
                                                    int* __restrict__ bBase,
                                                    int* __restrict__ startv) {
    __shared__ int s[NBUCK + 1];
    int tid = threadIdx.x;
    if (tid < NBUCK) s[tid] = bCnt[tid];
    __syncthreads();
    if (tid == 0) {
        int acc = 0;
        for (int i = 0; i < NBUCK; ++i) { int v = s[i]; s[i] = acc; acc += v; }
        s[NBUCK] = acc;
        startv[M_SEG] = acc;            // sentinel
    }
    __syncthreads();
    if (tid < NBUCK + 1) bBase[tid] = s[tid];
}

// ---------------------------------------------------------------- scatterB: deterministic bucket placement
__global__ __launch_bounds__(256) void scatterB(const int* __restrict__ edges,
                                                const int* __restrict__ H,
                                                const int* __restrict__ bBase,
                                                int* __restrict__ bpack) {
    __shared__ int sbase[NPART];
    __shared__ int cur[NPART];
    int bi  = blockIdx.x / NBLKB;
    int blk = blockIdx.x - bi * NBLKB;
    const int* rows = edges + ((size_t)bi * 2 + 0) * N_EDGESC;
    const int* cols = edges + ((size_t)bi * 2 + 1) * N_EDGESC;
    if (threadIdx.x < NPART) {
        int b = bi * NPART + threadIdx.x;
        sbase[threadIdx.x] = bBase[b] + H[b * NBLKB + blk];
        cur[threadIdx.x] = 0;
    }
    __syncthreads();
    int base0 = blk * EPB;
    for (int it = 0; it < EPB / 256; ++it) {
        int idx = base0 + it * 256 + threadIdx.x;
        if (idx < N_EDGESC) {
            int c = cols[idx];
            int r = rows[idx];
            int p = c / PSIZE;
            int rank = atomicAdd(&cur[p], 1);
            bpack[sbase[p] + rank] = ((c - p * PSIZE) << 18) | r;
        }
    }
}

// ---------------------------------------------------------------- place: one block per bucket
__global__ __launch_bounds__(256) void place_kernel(const int* __restrict__ bpack,
                                                    const int* __restrict__ bBase,
                                                    int* __restrict__ startv,
                                                    float* __restrict__ dinv,
                                                    int* __restrict__ srow) {
    __shared__ int cnt[PSIZE + 2];
    __shared__ int tsum[256];
    int b    = blockIdx.x;
    int bi   = b / NPART;
    int part = b - bi * NPART;
    int segBase = bi * N_NODES + part * PSIZE;
    int lo = bBase[b], hiEnd = bBase[b + 1];

    for (int i = threadIdx.x; i < PSIZE + 1; i += 256) cnt[i] = 0;
    __syncthreads();
    for (int i = lo + threadIdx.x; i < hiEnd; i += 256)
        atomicAdd(&cnt[bpack[i] >> 18], 1);
    __syncthreads();

    int t = threadIdx.x;
    int base0 = t * 13;
    int sum = 0;
#pragma unroll
    for (int k = 0; k < 13; ++k) {
        int i = base0 + k;
        if (i <= PSIZE) sum += cnt[i];
    }
    tsum[t] = sum;
    __syncthreads();
    for (int off = 1; off < 256; off <<= 1) {
        int v = (t >= off) ? tsum[t - off] : 0;
        __syncthreads();
        tsum[t] += v;
        __syncthreads();
    }
    int run = tsum[t] - sum;
    int vals[13];
#pragma unroll
    for (int k = 0; k < 13; ++k) {
        int i = base0 + k;
        vals[k] = (i <= PSIZE) ? cnt[i] : 0;
    }
    __syncthreads();
#pragma unroll
    for (int k = 0; k < 13; ++k) {
        int i = base0 + k;
        if (i <= PSIZE) { cnt[i] = run; run += vals[k]; }
    }
    __syncthreads();

    for (int i = threadIdx.x; i < PSIZE; i += 256) {
        int excl = cnt[i];
        int d    = cnt[i + 1] - excl;
        startv[segBase + i] = lo + excl;
        dinv[segBase + i]   = (d > 0) ? rsqrtf((float)d) : 0.0f;
    }
    __syncthreads();

    for (int i = lo + threadIdx.x; i < hiEnd; i += 256) {
        int pk  = bpack[i];
        int pos = atomicAdd(&cnt[pk >> 18], 1);
        srow[lo + pos] = pk & 0x3FFFF;
    }
}

// ---------------------------------------------------------------- gemm16_first: x16 = bf16( concat(ue,ie) @ W0 )
// reads f32 embeddings directly (no init copy); fuses reg-loss sumsq as
// per-block partial store (no atomics).
__global__ __launch_bounds__(256) void gemm16_first(const float* __restrict__ ue,
                                                    const float* __restrict__ ie,
                                                    const float* __restrict__ W,
                                                    u16* __restrict__ x16,
                                                    float* __restrict__ regpart) {
    __shared__ float wsum[4];
    int j = threadIdx.x & 63;
    float w[64];
#pragma unroll
    for (int k = 0; k < 64; ++k) w[k] = W[k * 64 + j];
    int wave = blockIdx.x * 4 + (threadIdx.x >> 6);
    int r0 = wave * GEMM_RPW;
    int r1 = r0 + GEMM_RPW; if (r1 > N_NODES) r1 = N_NODES;
    float sq = 0.0f;
    for (int r = r0; r < r1; ++r) {
        const float4* row = (r < N_USERS)
            ? (const float4*)(ue + (size_t)r * 64)
            : (const float4*)(ie + (size_t)(r - N_USERS) * 64);
        float acc = 0.0f;
#pragma unroll
        for (int k4 = 0; k4 < 16; ++k4) {
            float4 q = row[k4];
            acc += q.x * w[4 * k4 + 0] + q.y * w[4 * k4 + 1] +
                   q.z * w[4 * k4 + 2] + q.w * w[4 * k4 + 3];
            sq  += q.x * q.x + q.y * q.y + q.z * q.z + q.w * q.w;
        }
        x16[(size_t)r * 64 + j] = f2b(acc);
    }
    // sq is identical across lanes (wave-uniform loads)
    if ((threadIdx.x & 63) == 0) wsum[threadIdx.x >> 6] = sq;
    __syncthreads();
    if (threadIdx.x == 0)
        regpart[blockIdx.x] = (wsum[0] + wsum[1] + wsum[2] + wsum[3]) *
                              (0.5f * 0.0001f / (float)BATCH);
}

// ---------------------------------------------------------------- gemm16: x16 = bf16( g16 @ W )
__global__ __launch_bounds__(256) void gemm16(const ushort4* __restrict__ g16in,
                                              const float* __restrict__ W,
                                              u16* __restrict__ x16) {
    int j = threadIdx.x & 63;
    float w[64];
#pragma unroll
    for (int k = 0; k < 64; ++k) w[k] = W[k * 64 + j];
    int wave = blockIdx.x * 4 + (threadIdx.x >> 6);
    int r0 = wave * GEMM_RPW;
    int r1 = r0 + GEMM_RPW; if (r1 > N_NODES) r1 = N_NODES;
    for (int r = r0; r < r1; ++r) {
        const uint4* row = (const uint4*)(g16in + (size_t)r * 16);
        float acc = 0.0f;
#pragma unroll
        for (int k8 = 0; k8 < 8; ++k8) {
            uint4 q = row[k8];
            acc += __uint_as_float(q.x << 16)         * w[8 * k8 + 0];
            acc += __uint_as_float(q.x & 0xFFFF0000u) * w[8 * k8 + 1];
            acc += __uint_as_float(q.y << 16)         * w[8 * k8 + 2];
            acc += __uint_as_float(q.y & 0xFFFF0000u) * w[8 * k8 + 3];
            acc += __uint_as_float(q.z << 16)         * w[8 * k8 + 4];
            acc += __uint_as_float(q.z & 0xFFFF0000u) * w[8 * k8 + 5];
            acc += __uint_as_float(q.w << 16)         * w[8 * k8 + 6];
            acc += __uint_as_float(q.w & 0xFFFF0000u) * w[8 * k8 + 7];
        }
        x16[(size_t)r * 64 + j] = f2b(acc);
    }
}

// ---------------------------------------------------------------- agg: gather-sum + bias + l2norm + residual
// 4 nodes/wave (one per 16-lane subgroup); 8-edge unroll => 24 loads in flight.
// residual source = reslo/reshi (ue/ie on layer 0, total afterwards).
__global__ __launch_bounds__(256) void agg_kernel(const int* __restrict__ srow,
                                                  const int* __restrict__ startv,
                                                  const float* __restrict__ dinv,
                                                  const ushort4* __restrict__ x16,
                                                  const float* __restrict__ reslo,
                                                  const float* __restrict__ reshi,
                                                  float* __restrict__ total,
                                                  ushort4* __restrict__ g16out,
                                                  const float* __restrict__ bias,
                                                  int base /* bi*N_NODES */) {
    int lane = threadIdx.x & 63;
    int sub  = lane >> 4;
    int li   = lane & 15;
    int c = (blockIdx.x * 4 + (threadIdx.x >> 6)) * 4 + sub;   // < 200000 exact

    int   s   = startv[base + c];
    int   end = startv[base + c + 1];
    float dc  = dinv[base + c];
    float4 acc = {0.f, 0.f, 0.f, 0.f};
    for (int e = s; e < end; e += 8) {
#pragma unroll
        for (int jj = 0; jj < 8; ++jj) {
            int  ej = e + jj;
            bool ok = ej < end;
            int  ec = ok ? ej : s;
            int  r  = srow[ec];
            float n = ok ? dinv[base + r] : 0.0f;
            ushort4 a = x16[(size_t)r * 16 + li];
            acc.x += n * b2f(a.x); acc.y += n * b2f(a.y);
            acc.z += n * b2f(a.z); acc.w += n * b2f(a.w);
        }
    }
    float4 b = ((const float4*)bias)[li];
    float4 v;
    v.x = acc.x * dc + b.x; v.y = acc.y * dc + b.y;
    v.z = acc.z * dc + b.z; v.w = acc.w * dc + b.w;
    float sq = v.x * v.x + v.y * v.y + v.z * v.z + v.w * v.w;
#pragma unroll
    for (int off = 1; off < 16; off <<= 1) sq += __shfl_xor(sq, off, 64);
    float inv = 1.0f / fmaxf(sqrtf(sq), 1e-12f);
    const float4* rsrc = (c < N_USERS)
        ? (const float4*)reslo + (size_t)c * 16 + li
        : (const float4*)reshi + (size_t)(c - N_USERS) * 16 + li;
    float4 t = *rsrc;
    t.x += v.x * inv; t.y += v.y * inv; t.z += v.z * inv; t.w += v.w * inv;
    size_t idx = (size_t)c * 16 + li;
    ((float4*)total)[idx] = t;
    ushort4 h; h.x = f2b(t.x); h.y = f2b(t.y); h.z = f2b(t.z); h.w = f2b(t.w);
    g16out[idx] = h;
}

// ---------------------------------------------------------------- BPR loss (per-block partial, no atomics)
__global__ __launch_bounds__(256) void bpr_kernel(const float* __restrict__ total,
                                                  const int* __restrict__ batch,
                                                  int bi, float* __restrict__ bprpart) {
    __shared__ float sp4[4];
    int b    = blockIdx.x * 4 + (threadIdx.x >> 6);   // 1024 blocks, 4 samples each
    int lane = threadIdx.x & 63;
    int u  = batch[((size_t)b * NB + bi) * 3 + 0];
    int i0 = batch[((size_t)b * NB + bi) * 3 + 1];
    int i1 = batch[((size_t)b * NB + bi) * 3 + 2];
    float uf = total[(size_t)u * 64 + lane];
    float f0 = total[(size_t)(N_USERS + i0) * 64 + lane];
    float f1 = total[(size_t)(N_USERS + i1) * 64 + lane];
    float d  = uf * (f0 - f1);
#pragma unroll
    for (int off = 32; off; off >>= 1) d += __shfl_xor(d, off, 64);
    float sp = (d > 0.0f) ? log1pf(expf(-d)) : (-d + log1pf(expf(d)));
    if (lane == 0) sp4[threadIdx.x >> 6] = sp;
    __syncthreads();
    if (threadIdx.x == 0)
        bprpart[blockIdx.x] = (sp4[0] + sp4[1] + sp4[2] + sp4[3]) * (1.0f / BATCH);
}

// ---------------------------------------------------------------- final: reduce all partials
__global__ __launch_bounds__(256) void final_write(const float* __restrict__ parts,
                                                   float* __restrict__ out) {
    __shared__ float ws[4];
    float s = 0.0f;
    for (int i = threadIdx.x; i < NPARTS; i += 256) s += parts[i];
#pragma unroll
    for (int off = 32; off; off >>= 1) s += __shfl_xor(s, off, 64);
    if ((threadIdx.x & 63) == 0) ws[threadIdx.x >> 6] = s;
    __syncthreads();
    if (threadIdx.x == 0) out[0] = ws[0] + ws[1] + ws[2] + ws[3];
}

extern "C" void kernel_launch(void* const* d_in, const int* in_sizes, int n_in,
                              void* d_out, int out_size, void* d_ws, size_t ws_size,
                              hipStream_t stream) {
    const float* user_emb = (const float*)d_in[0];
    const float* item_emb = (const float*)d_in[1];
    const float* gcn_w    = (const float*)d_in[2];
    const float* gcn_b    = (const float*)d_in[3];
    const int*   edges    = (const int*)d_in[4];
    const int*   batch    = (const int*)d_in[5];
    float*       out      = (float*)d_out;

    const size_t NODE_F = (size_t)N_NODES * EMBED;            // 12.8M elems
    float*   total  = (float*)d_ws;                           // 51.2 MB f32 master
    ushort4* g16A   = (ushort4*)(total + NODE_F);             // 25.6 MB bf16 mirror A
    ushort4* g16B   = g16A + NODE_F / 4;                      // 25.6 MB bf16 mirror B
    u16*     x16    = (u16*)(g16B + NODE_F / 4);              // 25.6 MB bf16 gemm out
    float*   dinv   = (float*)(x16 + NODE_F);                 //  2.4 MB
    int*     startv = (int*)(dinv + M_SEG);                   //  2.4 MB (+1 sentinel)
    int*     Hglob  = startv + M_SEG + 1;                     //  98 KB
    int*     bCnt   = Hglob + NBUCK * NBLKB;                  //  768 B
    int*     bBase  = bCnt + NBUCK;                           //  772 B
    int*     bpack  = bBase + NBUCK + 1;                      //  24 MB
    int*     srow   = bpack + NE_TOT;                         //  24 MB
    float*   parts  = (float*)(srow + NE_TOT);                //  20 KB partials
    float*   regpart = parts;                                 //  [0, 2048)
    float*   bprpart = parts + GEMM_BLOCKS;                   //  [2048, 5120)

    // layer-0 GEMM first: reads restore-warm f32 inputs; fuses reg loss
    gemm16_first<<<GEMM_BLOCKS, 256, 0, stream>>>(user_emb, item_emb,
                                                  gcn_w, x16, regpart);

    // deterministic counting sort by destination column
    scatterA<<<NB * NBLKB, 256, 0, stream>>>(edges, Hglob);
    colscan<<<48, 256, 0, stream>>>(Hglob, bCnt);
    scan_buckets<<<1, 256, 0, stream>>>(bCnt, bBase, startv);
    scatterB<<<NB * NBLKB, 256, 0, stream>>>(edges, Hglob, bBase, bpack);
    place_kernel<<<NBUCK, 256, 0, stream>>>(bpack, bBase, startv, dinv, srow);

    // layer 0
    agg_kernel<<<AGG_BLOCKS, 256, 0, stream>>>(
        srow, startv, dinv, (const ushort4*)x16, user_emb, item_emb,
        total, g16A, gcn_b, 0);
    bpr_kernel<<<1024, 256, 0, stream>>>(total, batch, 0, bprpart);

    // layers 1, 2
    ushort4* gcur = g16A;
    ushort4* gnxt = g16B;
    for (int bi = 1; bi < NB; ++bi) {
        gemm16<<<GEMM_BLOCKS, 256, 0, stream>>>(
            gcur, gcn_w + (size_t)bi * EMBED * EMBED, x16);
        agg_kernel<<<AGG_BLOCKS, 256, 0, stream>>>(
            srow, startv, dinv, (const ushort4*)x16,
            total, total + (size_t)N_USERS * EMBED,
            total, gnxt, gcn_b + bi * EMBED, bi * N_NODES);
        bpr_kernel<<<1024, 256, 0, stream>>>(total, batch, bi, bprpart + bi * 1024);
        ushort4* t = gcur; gcur = gnxt; gnxt = t;
    }
    final_write<<<1, 256, 0, stream>>>(parts, out);
}

// Round 9
// 626.743 us; speedup vs baseline: 1.6676x; 1.3978x over previous
//
#include <hip/hip_runtime.h>

#define N_USERS  100000
#define N_ITEMS  100000
#define N_NODES  200000
#define EMBED    64
#define NB       3
#define N_EDGESC 2000000
#define NE_TOT   (NB * N_EDGESC)     // 6M
#define BATCH    4096
#define M_SEG    (NB * N_NODES)      // 600000 flat segments
#define NPART    64
#define PSIZE    3125                // N_NODES / NPART (exact)
#define NBUCK    (NB * NPART)        // 192
#define NBLKB    128                 // edge blocks per behavior (16384 edges each)
#define EPB      16384
#define GEMM_BLOCKS 3125             // 3125 blocks * 4 waves * 16 rows = 200000 exact
#define AGG_BLOCKS 12500             // 12500 * 16 nodes/block = 200000 exact
#define NPARTS   (GEMM_BLOCKS + NB * 1024)   // 3125 reg + 3072 bpr

typedef unsigned short u16;
typedef __attribute__((ext_vector_type(8))) short short8;   // 8 bf16 (4 VGPRs)
typedef __attribute__((ext_vector_type(4))) float f32x4;    // MFMA acc

__device__ __forceinline__ float b2f(u16 h) {
    return __uint_as_float(((unsigned)h) << 16);
}
__device__ __forceinline__ u16 f2b(float f) {
    unsigned u = __float_as_uint(f);
    return (u16)((u + 0x7FFF + ((u >> 16) & 1)) >> 16);   // RNE
}

// ---------------------------------------------------------------- scatterA: per-(bucket,block) hist
__global__ __launch_bounds__(256) void scatterA(const int* __restrict__ edges,
                                                int* __restrict__ H) {
    __shared__ int h[NPART];
    int bi  = blockIdx.x / NBLKB;
    int blk = blockIdx.x - bi * NBLKB;
    const int* cols = edges + ((size_t)bi * 2 + 1) * N_EDGESC;
    if (threadIdx.x < NPART) h[threadIdx.x] = 0;
    __syncthreads();
    int base0 = blk * EPB;
#pragma unroll 4
    for (int it = 0; it < EPB / 256; ++it) {
        int idx = base0 + it * 256 + threadIdx.x;
        if (idx < N_EDGESC) atomicAdd(&h[cols[idx] / PSIZE], 1);
    }
    __syncthreads();
    if (threadIdx.x < NPART)
        H[(bi * NPART + threadIdx.x) * NBLKB + blk] = h[threadIdx.x];
}

// ---------------------------------------------------------------- colscan
__global__ __launch_bounds__(256) void colscan(int* __restrict__ H,
                                               int* __restrict__ bCnt) {
    int wid = blockIdx.x * 4 + (threadIdx.x >> 6);
    if (wid >= NBUCK) return;
    int lane = threadIdx.x & 63;
    int i0 = wid * NBLKB + lane, i1 = i0 + 64;
    int v0 = H[i0], v1 = H[i1];
    int s0 = v0;
#pragma unroll
    for (int off = 1; off < 64; off <<= 1) {
        int t = __shfl_up(s0, off, 64);
        if (lane >= off) s0 += t;
    }
    int t0 = __shfl(s0, 63, 64);
    int s1 = v1;
#pragma unroll
    for (int off = 1; off < 64; off <<= 1) {
        int t = __shfl_up(s1, off, 64);
        if (lane >= off) s1 += t;
    }
    H[i0] = s0 - v0;
    H[i1] = t0 + s1 - v1;
    if (lane == 63) bCnt[wid] = t0 + s1;
}

// ---------------------------------------------------------------- scan 192 buckets
__global__ __launch_bounds__(256) void scan_buckets(const int* __restrict__ bCnt,
                                                    int* __restrict__ bBase,
                                                    int* __restrict__ startv) {
    __shared__ int s[NBUCK + 1];
    int tid = threadIdx.x;
    if (tid < NBUCK) s[tid] = bCnt[tid];
    __syncthreads();
    if (tid == 0) {
        int acc = 0;
        for (int i = 0; i < NBUCK; ++i) { int v = s[i]; s[i] = acc; acc += v; }
        s[NBUCK] = acc;
        startv[M_SEG] = acc;            // sentinel
    }
    __syncthreads();
    if (tid < NBUCK + 1) bBase[tid] = s[tid];
}

// ---------------------------------------------------------------- scatterB: deterministic bucket placement
__global__ __launch_bounds__(256) void scatterB(const int* __restrict__ edges,
                                                const int* __restrict__ H,
                                                const int* __restrict__ bBase,
                                                int* __restrict__ bpack) {
    __shared__ int sbase[NPART];
    __shared__ int cur[NPART];
    int bi  = blockIdx.x / NBLKB;
    int blk = blockIdx.x - bi * NBLKB;
    const int* rows = edges + ((size_t)bi * 2 + 0) * N_EDGESC;
    const int* cols = edges + ((size_t)bi * 2 + 1) * N_EDGESC;
    if (threadIdx.x < NPART) {
        int b = bi * NPART + threadIdx.x;
        sbase[threadIdx.x] = bBase[b] + H[b * NBLKB + blk];
        cur[threadIdx.x] = 0;
    }
    __syncthreads();
    int base0 = blk * EPB;
    for (int it = 0; it < EPB / 256; ++it) {
        int idx = base0 + it * 256 + threadIdx.x;
        if (idx < N_EDGESC) {
            int c = cols[idx];
            int r = rows[idx];
            int p = c / PSIZE;
            int rank = atomicAdd(&cur[p], 1);
            bpack[sbase[p] + rank] = ((c - p * PSIZE) << 18) | r;
        }
    }
}

// ---------------------------------------------------------------- place: one block per bucket
__global__ __launch_bounds__(256) void place_kernel(const int* __restrict__ bpack,
                                                    const int* __restrict__ bBase,
                                                    int* __restrict__ startv,
                                                    float* __restrict__ dinv,
                                                    int* __restrict__ srow) {
    __shared__ int cnt[PSIZE + 2];
    __shared__ int tsum[256];
    int b    = blockIdx.x;
    int bi   = b / NPART;
    int part = b - bi * NPART;
    int segBase = bi * N_NODES + part * PSIZE;
    int lo = bBase[b], hiEnd = bBase[b + 1];

    for (int i = threadIdx.x; i < PSIZE + 1; i += 256) cnt[i] = 0;
    __syncthreads();
    for (int i = lo + threadIdx.x; i < hiEnd; i += 256)
        atomicAdd(&cnt[bpack[i] >> 18], 1);
    __syncthreads();

    int t = threadIdx.x;
    int base0 = t * 13;
    int sum = 0;
#pragma unroll
    for (int k = 0; k < 13; ++k) {
        int i = base0 + k;
        if (i <= PSIZE) sum += cnt[i];
    }
    tsum[t] = sum;
    __syncthreads();
    for (int off = 1; off < 256; off <<= 1) {
        int v = (t >= off) ? tsum[t - off] : 0;
        __syncthreads();
        tsum[t] += v;
        __syncthreads();
    }
    int run = tsum[t] - sum;
    int vals[13];
#pragma unroll
    for (int k = 0; k < 13; ++k) {
        int i = base0 + k;
        vals[k] = (i <= PSIZE) ? cnt[i] : 0;
    }
    __syncthreads();
#pragma unroll
    for (int k = 0; k < 13; ++k) {
        int i = base0 + k;
        if (i <= PSIZE) { cnt[i] = run; run += vals[k]; }
    }
    __syncthreads();

    for (int i = threadIdx.x; i < PSIZE; i += 256) {
        int excl = cnt[i];
        int d    = cnt[i + 1] - excl;
        startv[segBase + i] = lo + excl;
        dinv[segBase + i]   = (d > 0) ? rsqrtf((float)d) : 0.0f;
    }
    __syncthreads();

    for (int i = lo + threadIdx.x; i < hiEnd; i += 256) {
        int pk  = bpack[i];
        int pos = atomicAdd(&cnt[pk >> 18], 1);
        srow[lo + pos] = pk & 0x3FFFF;
    }
}

// ---------------------------------------------------------------- B-fragment loader: Bf[ct][kt] = bf16 W[k][ct*16+n]
// layout per m120: B[k = quad*8 + j][n = lane&15]
__device__ __forceinline__ void load_Bfrag(const float* __restrict__ W,
                                           int lane, short8 Bf[4][2]) {
    int n    = lane & 15;
    int kb   = (lane >> 4) * 8;
#pragma unroll
    for (int ct = 0; ct < 4; ++ct)
#pragma unroll
        for (int kt = 0; kt < 2; ++kt)
#pragma unroll
            for (int j = 0; j < 8; ++j)
                Bf[ct][kt][j] = (short)f2b(W[(kt * 32 + kb + j) * 64 + ct * 16 + n]);
}

// ---------------------------------------------------------------- MFMA store: C/D col=lane&15, row=quad*4+reg
__device__ __forceinline__ void store_tile(u16* __restrict__ x16, int r0, int lane,
                                           const f32x4 acc[4]) {
    int col  = lane & 15;
    int rowb = (lane >> 4) * 4;
#pragma unroll
    for (int ct = 0; ct < 4; ++ct)
#pragma unroll
        for (int j = 0; j < 4; ++j)
            x16[(size_t)(r0 + rowb + j) * 64 + ct * 16 + col] = f2b(acc[ct][j]);
}

// ---------------------------------------------------------------- mfma_first: x16 = bf16(concat(ue,ie) @ W0), fused reg loss
__global__ __launch_bounds__(256) void mfma_first(const float* __restrict__ ue,
                                                  const float* __restrict__ ie,
                                                  const float* __restrict__ W,
                                                  u16* __restrict__ x16,
                                                  float* __restrict__ regpart) {
    __shared__ float wsum[4];
    int lane = threadIdx.x & 63;
    short8 Bf[4][2];
    load_Bfrag(W, lane, Bf);

    int r0 = (blockIdx.x * 4 + (threadIdx.x >> 6)) * 16;
    int m  = lane & 15;
    int kb = (lane >> 4) * 8;
    int r  = r0 + m;
    const float* src = (r < N_USERS) ? (ue + (size_t)r * 64)
                                     : (ie + (size_t)(r - N_USERS) * 64);
    // A fragments: A[m][k=kb+j] (kt0), A[m][32+kb+j] (kt1); 8 f32 -> short8 each
    float sq = 0.0f;
    short8 A0, A1;
#pragma unroll
    for (int h = 0; h < 2; ++h) {
        float4 a = ((const float4*)(src + h * 32 + kb))[0];
        float4 b = ((const float4*)(src + h * 32 + kb))[1];
        short8& A = h ? A1 : A0;
        A[0] = (short)f2b(a.x); A[1] = (short)f2b(a.y);
        A[2] = (short)f2b(a.z); A[3] = (short)f2b(a.w);
        A[4] = (short)f2b(b.x); A[5] = (short)f2b(b.y);
        A[6] = (short)f2b(b.z); A[7] = (short)f2b(b.w);
        sq += a.x * a.x + a.y * a.y + a.z * a.z + a.w * a.w;
        sq += b.x * b.x + b.y * b.y + b.z * b.z + b.w * b.w;
    }
    f32x4 acc[4];
#pragma unroll
    for (int ct = 0; ct < 4; ++ct) {
        acc[ct] = (f32x4){0.f, 0.f, 0.f, 0.f};
        acc[ct] = __builtin_amdgcn_mfma_f32_16x16x32_bf16(A0, Bf[ct][0], acc[ct], 0, 0, 0);
        acc[ct] = __builtin_amdgcn_mfma_f32_16x16x32_bf16(A1, Bf[ct][1], acc[ct], 0, 0, 0);
    }
    store_tile(x16, r0, lane, acc);

#pragma unroll
    for (int off = 32; off; off >>= 1) sq += __shfl_xor(sq, off, 64);
    if (lane == 0) wsum[threadIdx.x >> 6] = sq;
    __syncthreads();
    if (threadIdx.x == 0)
        regpart[blockIdx.x] = (wsum[0] + wsum[1] + wsum[2] + wsum[3]) *
                              (0.5f * 0.0001f / (float)BATCH);
}

// ---------------------------------------------------------------- mfma_gemm: x16 = bf16( g16 @ W )
__global__ __launch_bounds__(256) void mfma_gemm(const u16* __restrict__ g16,
                                                 const float* __restrict__ W,
                                                 u16* __restrict__ x16) {
    int lane = threadIdx.x & 63;
    short8 Bf[4][2];
    load_Bfrag(W, lane, Bf);

    int r0 = (blockIdx.x * 4 + (threadIdx.x >> 6)) * 16;
    int m  = lane & 15;
    int kb = (lane >> 4) * 8;
    const u16* src = g16 + (size_t)(r0 + m) * 64 + kb;
    short8 A0 = *(const short8*)(src);
    short8 A1 = *(const short8*)(src + 32);
    f32x4 acc[4];
#pragma unroll
    for (int ct = 0; ct < 4; ++ct) {
        acc[ct] = (f32x4){0.f, 0.f, 0.f, 0.f};
        acc[ct] = __builtin_amdgcn_mfma_f32_16x16x32_bf16(A0, Bf[ct][0], acc[ct], 0, 0, 0);
        acc[ct] = __builtin_amdgcn_mfma_f32_16x16x32_bf16(A1, Bf[ct][1], acc[ct], 0, 0, 0);
    }
    store_tile(x16, r0, lane, acc);
}

// ---------------------------------------------------------------- agg: gather-sum + bias + l2norm + residual
// 4 nodes/wave (one per 16-lane subgroup); 8-edge unroll => 24 loads in flight.
__global__ __launch_bounds__(256) void agg_kernel(const int* __restrict__ srow,
                                                  const int* __restrict__ startv,
                                                  const float* __restrict__ dinv,
                                                  const ushort4* __restrict__ x16,
                                                  const float* __restrict__ reslo,
                                                  const float* __restrict__ reshi,
                                                  float* __restrict__ total,
                                                  ushort4* __restrict__ g16out,
                                                  const float* __restrict__ bias,
                                                  int base /* bi*N_NODES */) {
    int lane = threadIdx.x & 63;
    int sub  = lane >> 4;
    int li   = lane & 15;
    int c = (blockIdx.x * 4 + (threadIdx.x >> 6)) * 4 + sub;   // < 200000 exact

    int   s   = startv[base + c];
    int   end = startv[base + c + 1];
    float dc  = dinv[base + c];
    float4 acc = {0.f, 0.f, 0.f, 0.f};
    for (int e = s; e < end; e += 8) {
#pragma unroll
        for (int jj = 0; jj < 8; ++jj) {
            int  ej = e + jj;
            bool ok = ej < end;
            int  ec = ok ? ej : s;
            int  r  = srow[ec];
            float n = ok ? dinv[base + r] : 0.0f;
            ushort4 a = x16[(size_t)r * 16 + li];
            acc.x += n * b2f(a.x); acc.y += n * b2f(a.y);
            acc.z += n * b2f(a.z); acc.w += n * b2f(a.w);
        }
    }
    float4 b = ((const float4*)bias)[li];
    float4 v;
    v.x = acc.x * dc + b.x; v.y = acc.y * dc + b.y;
    v.z = acc.z * dc + b.z; v.w = acc.w * dc + b.w;
    float sq = v.x * v.x + v.y * v.y + v.z * v.z + v.w * v.w;
#pragma unroll
    for (int off = 1; off < 16; off <<= 1) sq += __shfl_xor(sq, off, 64);
    float inv = 1.0f / fmaxf(sqrtf(sq), 1e-12f);
    const float4* rsrc = (c < N_USERS)
        ? (const float4*)reslo + (size_t)c * 16 + li
        : (const float4*)reshi + (size_t)(c - N_USERS) * 16 + li;
    float4 t = *rsrc;
    t.x += v.x * inv; t.y += v.y * inv; t.z += v.z * inv; t.w += v.w * inv;
    size_t idx = (size_t)c * 16 + li;
    ((float4*)total)[idx] = t;
    ushort4 h; h.x = f2b(t.x); h.y = f2b(t.y); h.z = f2b(t.z); h.w = f2b(t.w);
    g16out[idx] = h;
}

// ---------------------------------------------------------------- BPR loss (per-block partial, no atomics)
__global__ __launch_bounds__(256) void bpr_kernel(const float* __restrict__ total,
                                                  const int* __restrict__ batch,
                                                  int bi, float* __restrict__ bprpart) {
    __shared__ float sp4[4];
    int b    = blockIdx.x * 4 + (threadIdx.x >> 6);   // 1024 blocks, 4 samples each
    int lane = threadIdx.x & 63;
    int u  = batch[((size_t)b * NB + bi) * 3 + 0];
    int i0 = batch[((size_t)b * NB + bi) * 3 + 1];
    int i1 = batch[((size_t)b * NB + bi) * 3 + 2];
    float uf = total[(size_t)u * 64 + lane];
    float f0 = total[(size_t)(N_USERS + i0) * 64 + lane];
    float f1 = total[(size_t)(N_USERS + i1) * 64 + lane];
    float d  = uf * (f0 - f1);
#pragma unroll
    for (int off = 32; off; off >>= 1) d += __shfl_xor(d, off, 64);
    float sp = (d > 0.0f) ? log1pf(expf(-d)) : (-d + log1pf(expf(d)));
    if (lane == 0) sp4[threadIdx.x >> 6] = sp;
    __syncthreads();
    if (threadIdx.x == 0)
        bprpart[blockIdx.x] = (sp4[0] + sp4[1] + sp4[2] + sp4[3]) * (1.0f / BATCH);
}

// ---------------------------------------------------------------- final: reduce all partials
__global__ __launch_bounds__(256) void final_write(const float* __restrict__ parts,
                                                   float* __restrict__ out) {
    __shared__ float ws[4];
    float s = 0.0f;
    for (int i = threadIdx.x; i < NPARTS; i += 256) s += parts[i];
#pragma unroll
    for (int off = 32; off; off >>= 1) s += __shfl_xor(s, off, 64);
    if ((threadIdx.x & 63) == 0) ws[threadIdx.x >> 6] = s;
    __syncthreads();
    if (threadIdx.x == 0) out[0] = ws[0] + ws[1] + ws[2] + ws[3];
}

extern "C" void kernel_launch(void* const* d_in, const int* in_sizes, int n_in,
                              void* d_out, int out_size, void* d_ws, size_t ws_size,
                              hipStream_t stream) {
    const float* user_emb = (const float*)d_in[0];
    const float* item_emb = (const float*)d_in[1];
    const float* gcn_w    = (const float*)d_in[2];
    const float* gcn_b    = (const float*)d_in[3];
    const int*   edges    = (const int*)d_in[4];
    const int*   batch    = (const int*)d_in[5];
    float*       out      = (float*)d_out;

    const size_t NODE_F = (size_t)N_NODES * EMBED;            // 12.8M elems
    float*   total  = (float*)d_ws;                           // 51.2 MB f32 master
    ushort4* g16A   = (ushort4*)(total + NODE_F);             // 25.6 MB bf16 mirror A
    ushort4* g16B   = g16A + NODE_F / 4;                      // 25.6 MB bf16 mirror B
    u16*     x16    = (u16*)(g16B + NODE_F / 4);              // 25.6 MB bf16 gemm out
    float*   dinv   = (float*)(x16 + NODE_F);                 //  2.4 MB
    int*     startv = (int*)(dinv + M_SEG);                   //  2.4 MB (+1 sentinel)
    int*     Hglob  = startv + M_SEG + 1;                     //  98 KB
    int*     bCnt   = Hglob + NBUCK * NBLKB;                  //  768 B
    int*     bBase  = bCnt + NBUCK;                           //  772 B
    int*     bpack  = bBase + NBUCK + 1;                      //  24 MB
    int*     srow   = bpack + NE_TOT;                         //  24 MB
    float*   parts  = (float*)(srow + NE_TOT);                //  25 KB partials
    float*   regpart = parts;                                 //  [0, 3125)
    float*   bprpart = parts + GEMM_BLOCKS;                   //  [3125, 3125+3072)

    // layer-0 GEMM via MFMA: reads restore-warm f32 inputs; fuses reg loss
    mfma_first<<<GEMM_BLOCKS, 256, 0, stream>>>(user_emb, item_emb,
                                                gcn_w, x16, regpart);

    // deterministic counting sort by destination column
    scatterA<<<NB * NBLKB, 256, 0, stream>>>(edges, Hglob);
    colscan<<<48, 256, 0, stream>>>(Hglob, bCnt);
    scan_buckets<<<1, 256, 0, stream>>>(bCnt, bBase, startv);
    scatterB<<<NB * NBLKB, 256, 0, stream>>>(edges, Hglob, bBase, bpack);
    place_kernel<<<NBUCK, 256, 0, stream>>>(bpack, bBase, startv, dinv, srow);

    // layer 0
    agg_kernel<<<AGG_BLOCKS, 256, 0, stream>>>(
        srow, startv, dinv, (const ushort4*)x16, user_emb, item_emb,
        total, g16A, gcn_b, 0);
    bpr_kernel<<<1024, 256, 0, stream>>>(total, batch, 0, bprpart);

    // layers 1, 2
    ushort4* gcur = g16A;
    ushort4* gnxt = g16B;
    for (int bi = 1; bi < NB; ++bi) {
        mfma_gemm<<<GEMM_BLOCKS, 256, 0, stream>>>(
            (const u16*)gcur, gcn_w + (size_t)bi * EMBED * EMBED, x16);
        agg_kernel<<<AGG_BLOCKS, 256, 0, stream>>>(
            srow, startv, dinv, (const ushort4*)x16,
            total, total + (size_t)N_USERS * EMBED,
            total, gnxt, gcn_b + bi * EMBED, bi * N_NODES);
        bpr_kernel<<<1024, 256, 0, stream>>>(total, batch, bi, bprpart + bi * 1024);
        ushort4* t = gcur; gcur = gnxt; gnxt = t;
    }
    final_write<<<1, 256, 0, stream>>>(parts, out);
}